// Round 7
// baseline (371.291 us; speedup 1.0000x reference)
//
#include <hip/hip_runtime.h>
#include <cstdint>
#include <cstddef>

// Problem constants (Qwen3VLMoeTextExperts): E=8, H=2048, I=768, T=B*S=4096
#define NE 8
#define NH 2048
#define NI 768
#define NT 4096
#define NK2 6144   // NE*NI : K of second GEMM

typedef __bf16 bf16x8 __attribute__((ext_vector_type(8)));
typedef float f32x4 __attribute__((ext_vector_type(4)));
typedef unsigned short u16x8 __attribute__((ext_vector_type(8)));

__device__ __forceinline__ unsigned short f2bf(float f) {
  unsigned int u = __builtin_bit_cast(unsigned int, f);
  u += 0x7fffu + ((u >> 16) & 1u);   // round-to-nearest-even
  return (unsigned short)(u >> 16);
}

// async global->LDS, 16B per lane (dest must be linear: base + lane*16).
__device__ __forceinline__ void gload_lds16(const void* g, void* s) {
  __builtin_amdgcn_global_load_lds(
      (const __attribute__((address_space(1))) unsigned int*)g,
      (__attribute__((address_space(3))) unsigned int*)s, 16, 0, 0);
}

// ---------------- convert f32 -> bf16 (vectorized x8) ----------------
__global__ __launch_bounds__(256) void k_cvt(const float* __restrict__ in,
                                             unsigned short* __restrict__ out,
                                             long n) {
  long i = ((long)blockIdx.x * blockDim.x + threadIdx.x) * 8;
  if (i >= n) return;
  float4 f0 = *reinterpret_cast<const float4*>(in + i);
  float4 f1 = *reinterpret_cast<const float4*>(in + i + 4);
  u16x8 o;
  o[0] = f2bf(f0.x); o[1] = f2bf(f0.y); o[2] = f2bf(f0.z); o[3] = f2bf(f0.w);
  o[4] = f2bf(f1.x); o[5] = f2bf(f1.y); o[6] = f2bf(f1.z); o[7] = f2bf(f1.w);
  *reinterpret_cast<u16x8*>(out + i) = o;
}

// ------------- transpose + convert: out[b*oBS + perm(c)*oCS + r] = in[b][r][c] -------------
// mode 0: perm = identity. mode 1 (gate_up): interleave gate/up at 16-col
// granularity: gate col c -> (c>>4)*32 + (c&15); up col c -> (c>>4)*32 + 16 + (c&15).
__global__ __launch_bounds__(256) void k_transpose_cvt(
    const float* __restrict__ in, unsigned short* __restrict__ out,
    int R, int C, long inBS, long outBS, int outCS, int mode) {
  __shared__ float tile[32][33];
  const int b = blockIdx.z;
  const int r0 = blockIdx.y * 32, c0 = blockIdx.x * 32;
  const int tx = threadIdx.x, ty = threadIdx.y;
  const float* ib = in + (long)b * inBS;
#pragma unroll
  for (int d = 0; d < 4; d++)
    tile[ty + d * 8][tx] = ib[(long)(r0 + ty + d * 8) * C + c0 + tx];
  __syncthreads();
#pragma unroll
  for (int d = 0; d < 4; d++) {
    int c = c0 + ty + d * 8;   // original out-major index
    int r = r0 + tx;           // out minor index (coalesced)
    int orow;
    if (mode == 1) {
      int z = (c >= NI) ? 1 : 0;
      int cc = c - z * NI;
      orow = ((cc >> 4) << 5) + (z << 4) + (cc & 15);
    } else {
      orow = c;
    }
    out[(long)b * outBS + (long)orow * outCS + r] = f2bf(tile[tx][ty + d * 8]);
  }
}

// ==================== GEMM1: 4-phase deep-cover pipeline, 256x256 ====================
// 8 waves: wr=wave>>2 (M), wc=wave&3 (N); per-wave out 128x64 (M-interleaved).
// rA(i)=(i>>2)*128+wr*64+(i&3)*16+fr, rB(j)=(j>>1)*128+wc*32+(j&1)*16+fr.
// Phases per K-tile t (buf=t&1), quadrants (IH,JH)=(0,0)(0,1)(1,1)(1,0):
//   ph1: read af0(8)+bf0(4); issue A1(t+1); vmcnt(10); BAR; 16 MFMA
//   ph2: read bf1(4);        issue A0(t+2); vmcnt(10); BAR; 16 MFMA
//   ph3: read af1(8);        issue B0(t+2);            BAR; 16 MFMA
//   ph4: (bf0 kept in regs); issue B1(t+2); vmcnt(10); BAR; 16 MFMA
// Stage unit = one operand-half (2 gloads). Unit issue order: A0(t)@ph2(t-2),
// B0(t)@ph3(t-2), B1(t)@ph4(t-2), A1(t)@ph1(t-1) -> every unit has 5 phases
// of HBM-latency cover before the vmcnt that retires it:
//   ph1(t) vmcnt(10) retires B1(t)   (certifies ph2's bf1 reads)
//   ph2(t) vmcnt(10) retires A1(t)   (certifies ph3's af1 reads)
//   ph4(t) vmcnt(10) retires A0(t+1),B0(t+1) (certifies ph1(t+1) reads)
// Reads are always issued after the vmcnt+barrier pair that certified them
// (collective certification = per-wave vmcnt + s_barrier).
// Tail: units with tt>=nkt write garbage into dead regions of buf tt&1
// (source clamped to nkt-1); ledger stays uniform. 24 ds_read_b128/tile.
// Swizzle: chunk c of row r at c^(r&7), pre-swizzled global source; 0 conflicts.

__global__ __launch_bounds__(512, 1) void k_gemm1(
    const unsigned short* __restrict__ Xb,    // [NT][NH] bf16
    const unsigned short* __restrict__ W1t,   // [NE][1536(perm)][NH] bf16
    const float* __restrict__ rw,             // [NT][NE]
    unsigned short* __restrict__ inter) {     // [NT][NK2] bf16
  __shared__ unsigned short ldsA[2][16384];   // 2 x 32 KiB
  __shared__ unsigned short ldsB[2][16384];   // 2 x 32 KiB

  const int e = blockIdx.z;
  const int t0 = blockIdx.y * 256;
  const int bn = blockIdx.x;
  const int tid = threadIdx.x;
  const int lane = tid & 63, wave = tid >> 6;
  const int wr = wave >> 2, wc = wave & 3;
  const int fr = lane & 15, fq = lane >> 4;
  const int nkt = NH / 64;                   // 32

  const unsigned short* Bg = W1t + (size_t)e * (2 * NI) * NH;
  const int rih = tid >> 3, ck = tid & 7;
  const unsigned short* sA = Xb + (size_t)(t0 + rih) * NH + ((ck ^ (rih & 7)) << 3);
  const unsigned short* sB = Bg + (size_t)(bn * 256 + rih) * NH + ((ck ^ (rih & 7)) << 3);
  const int dst = tid * 8;

#define SRC_K(TT) ((size_t)(((TT) < nkt) ? (TT) : (nkt - 1)) * 64)
#define SU_A0(TT) do { unsigned short* L_ = ldsA[(TT) & 1]; const size_t k_ = SRC_K(TT); \
    gload_lds16(sA + k_,                       L_ + dst); \
    gload_lds16(sA + k_ + (size_t)64 * NH,     L_ + dst + 4096); } while (0)
#define SU_A1(TT) do { unsigned short* L_ = ldsA[(TT) & 1]; const size_t k_ = SRC_K(TT); \
    gload_lds16(sA + k_ + (size_t)128 * NH,    L_ + dst + 8192); \
    gload_lds16(sA + k_ + (size_t)192 * NH,    L_ + dst + 12288); } while (0)
#define SU_B0(TT) do { unsigned short* L_ = ldsB[(TT) & 1]; const size_t k_ = SRC_K(TT); \
    gload_lds16(sB + k_,                       L_ + dst); \
    gload_lds16(sB + k_ + (size_t)64 * NH,     L_ + dst + 4096); } while (0)
#define SU_B1(TT) do { unsigned short* L_ = ldsB[(TT) & 1]; const size_t k_ = SRC_K(TT); \
    gload_lds16(sB + k_ + (size_t)128 * NH,    L_ + dst + 8192); \
    gload_lds16(sB + k_ + (size_t)192 * NH,    L_ + dst + 12288); } while (0)
#define WAITV10 asm volatile("s_waitcnt vmcnt(10)" ::: "memory")
#define BAR do { __builtin_amdgcn_sched_barrier(0); \
                 __builtin_amdgcn_s_barrier(); \
                 __builtin_amdgcn_sched_barrier(0); } while (0)

  f32x4 acc[8][4];
#pragma unroll
  for (int i = 0; i < 8; ++i)
#pragma unroll
    for (int j = 0; j < 4; ++j) acc[i][j] = (f32x4){0.f, 0.f, 0.f, 0.f};

  const int swz = fr & 7;
  int aoff[8], boff[4];
#pragma unroll
  for (int i = 0; i < 8; ++i)
    aoff[i] = ((i >> 2) * 128 + wr * 64 + (i & 3) * 16 + fr) * 64 + ((fq ^ swz) << 3);
#pragma unroll
  for (int j = 0; j < 4; ++j)
    boff[j] = ((j >> 1) * 128 + wc * 32 + (j & 1) * 16 + fr) * 64 + ((fq ^ swz) << 3);
  const int dk = ((((4 + fq) ^ swz) - (fq ^ swz)) << 3);   // kk=1 frag delta

  // prologue: canonical issue order for everything preceding ph1(0); then
  // vmcnt(10) retires A0(0),B0(0) -> barrier -> steady-state loop.
  SU_A0(0); SU_B0(0); SU_B1(0); SU_A1(0); SU_A0(1); SU_B0(1); SU_B1(1);
  WAITV10;
  BAR;

  for (int kt = 0; kt < nkt; ++kt) {
    const int cur = kt & 1;
    const unsigned short* lA = ldsA[cur];
    const unsigned short* lB = ldsB[cur];
    bf16x8 af0[4][2], af1[4][2], bf0[2][2], bf1[2][2];

    // ---- ph1: quadrant (IH0,JH0) ----
#pragma unroll
    for (int m = 0; m < 4; ++m) {
      af0[m][0] = *reinterpret_cast<const bf16x8*>(lA + aoff[m]);
      af0[m][1] = *reinterpret_cast<const bf16x8*>(lA + aoff[m] + dk);
    }
#pragma unroll
    for (int jj = 0; jj < 2; ++jj) {
      bf0[jj][0] = *reinterpret_cast<const bf16x8*>(lB + boff[jj]);
      bf0[jj][1] = *reinterpret_cast<const bf16x8*>(lB + boff[jj] + dk);
    }
    SU_A1(kt + 1);
    WAITV10;
    BAR;
    __builtin_amdgcn_s_setprio(1);
#pragma unroll
    for (int kk = 0; kk < 2; ++kk)
#pragma unroll
      for (int m = 0; m < 4; ++m)
#pragma unroll
        for (int jj = 0; jj < 2; ++jj)
          acc[m][jj] = __builtin_amdgcn_mfma_f32_16x16x32_bf16(af0[m][kk], bf0[jj][kk], acc[m][jj], 0, 0, 0);
    __builtin_amdgcn_s_setprio(0);

    // ---- ph2: quadrant (IH0,JH1) ----
#pragma unroll
    for (int jj = 0; jj < 2; ++jj) {
      bf1[jj][0] = *reinterpret_cast<const bf16x8*>(lB + boff[2 + jj]);
      bf1[jj][1] = *reinterpret_cast<const bf16x8*>(lB + boff[2 + jj] + dk);
    }
    SU_A0(kt + 2);
    WAITV10;
    BAR;
    __builtin_amdgcn_s_setprio(1);
#pragma unroll
    for (int kk = 0; kk < 2; ++kk)
#pragma unroll
      for (int m = 0; m < 4; ++m)
#pragma unroll
        for (int jj = 0; jj < 2; ++jj)
          acc[m][2 + jj] = __builtin_amdgcn_mfma_f32_16x16x32_bf16(af0[m][kk], bf1[jj][kk], acc[m][2 + jj], 0, 0, 0);
    __builtin_amdgcn_s_setprio(0);

    // ---- ph3: quadrant (IH1,JH1) ----
#pragma unroll
    for (int m = 0; m < 4; ++m) {
      af1[m][0] = *reinterpret_cast<const bf16x8*>(lA + aoff[4 + m]);
      af1[m][1] = *reinterpret_cast<const bf16x8*>(lA + aoff[4 + m] + dk);
    }
    SU_B0(kt + 2);
    BAR;
    __builtin_amdgcn_s_setprio(1);
#pragma unroll
    for (int kk = 0; kk < 2; ++kk)
#pragma unroll
      for (int m = 0; m < 4; ++m)
#pragma unroll
        for (int jj = 0; jj < 2; ++jj)
          acc[4 + m][2 + jj] = __builtin_amdgcn_mfma_f32_16x16x32_bf16(af1[m][kk], bf1[jj][kk], acc[4 + m][2 + jj], 0, 0, 0);
    __builtin_amdgcn_s_setprio(0);

    // ---- ph4: quadrant (IH1,JH0), bf0 from regs, no ds_read ----
    SU_B1(kt + 2);
    WAITV10;
    BAR;
    __builtin_amdgcn_s_setprio(1);
#pragma unroll
    for (int kk = 0; kk < 2; ++kk)
#pragma unroll
      for (int m = 0; m < 4; ++m)
#pragma unroll
        for (int jj = 0; jj < 2; ++jj)
          acc[4 + m][jj] = __builtin_amdgcn_mfma_f32_16x16x32_bf16(af1[m][kk], bf0[jj][kk], acc[4 + m][jj], 0, 0, 0);
    __builtin_amdgcn_s_setprio(0);
  }
  asm volatile("s_waitcnt vmcnt(0)" ::: "memory");
#undef SRC_K
#undef SU_A0
#undef SU_A1
#undef SU_B0
#undef SU_B1
#undef WAITV10
#undef BAR

  // epilogue: silu(gate)*up*rw -> bf16.  acc[i][2p]=gate, acc[i][2p+1]=up for
  // inter col (within expert) = (p*4 + wc)*16 + fr; token row from rA(i).
#pragma unroll
  for (int i = 0; i < 8; ++i) {
    const int trow = t0 + (i >> 2) * 128 + wr * 64 + (i & 3) * 16 + fq * 4;
#pragma unroll
    for (int r = 0; r < 4; ++r) {
      const int t = trow + r;
      const float rwv = rw[(size_t)t * NE + e];
#pragma unroll
      for (int p = 0; p < 2; ++p) {
        float g = acc[i][2 * p][r];
        float u = acc[i][2 * p + 1][r];
        float s = g / (1.f + __expf(-g));  // silu
        const int col = bn * 128 + (p * 4 + wc) * 16 + fr;
        inter[(size_t)t * NK2 + e * NI + col] = f2bf(rwv * u * s);
      }
    }
  }
}

// ==================== GEMM2: kk-split structure (unchanged from R5), 256x128 ====================
__global__ __launch_bounds__(512, 2) void k_gemm2(
    const unsigned short* __restrict__ inter,  // [NT][NK2] bf16
    const unsigned short* __restrict__ W2t,    // [NH][NK2] bf16
    float* __restrict__ out) {                 // [NT][NH] f32
  __shared__ unsigned short ldsA[2][16384];    // 2 x 32 KiB (256x64)
  __shared__ unsigned short ldsB[2][8192];     // 2 x 16 KiB (128x64)

  const int t0 = blockIdx.y * 256;
  const int h0 = blockIdx.x * 128;
  const int tid = threadIdx.x;
  const int lane = tid & 63, wave = tid >> 6;
  const int wr = wave >> 1, wc = wave & 1;
  const int fr = lane & 15, fq = lane >> 4;
  const int nkt = NK2 / 64;                  // 96

  const int rih = tid >> 3, ck = tid & 7;
  const unsigned short* sA = inter + (size_t)(t0 + rih) * NK2 + ((ck ^ (rih & 7)) << 3);
  const unsigned short* sB = W2t + (size_t)(h0 + rih) * NK2 + ((ck ^ (rih & 7)) << 3);
  const int dst = tid * 8;

#define STG2(C) do { \
    const int cc_ = (C); \
    unsigned short* da_ = &ldsA[cc_ & 1][dst]; \
    unsigned short* db_ = &ldsB[cc_ & 1][dst]; \
    const size_t ko_ = (size_t)cc_ * 64; \
    _Pragma("unroll") \
    for (int q = 0; q < 4; ++q) \
      gload_lds16(sA + ko_ + (size_t)q * (64 * NK2), da_ + q * 4096); \
    _Pragma("unroll") \
    for (int q = 0; q < 2; ++q) \
      gload_lds16(sB + ko_ + (size_t)q * (64 * NK2), db_ + q * 4096); \
  } while (0)

  f32x4 acc[4][4];
#pragma unroll
  for (int i = 0; i < 4; ++i)
#pragma unroll
    for (int j = 0; j < 4; ++j) acc[i][j] = (f32x4){0.f, 0.f, 0.f, 0.f};

  const int swz = fr & 7;
  int aoff[4], boff[4];
#pragma unroll
  for (int i = 0; i < 4; ++i)
    aoff[i] = (wr * 64 + i * 16 + fr) * 64 + ((fq ^ swz) << 3);
#pragma unroll
  for (int j = 0; j < 4; ++j)
    boff[j] = (wc * 64 + j * 16 + fr) * 64 + ((fq ^ swz) << 3);
  const int dk = ((((4 + fq) ^ swz) - (fq ^ swz)) << 3);

  STG2(0);
  STG2(1);

  for (int kt = 0; kt < nkt; ++kt) {
    const int cur = kt & 1;
    const int nx = (kt + 1 < nkt) ? kt + 1 : nkt - 1;
    STG2(nx);
    asm volatile("s_waitcnt vmcnt(6)" ::: "memory");
    __builtin_amdgcn_sched_barrier(0);
    __builtin_amdgcn_s_barrier();
    __builtin_amdgcn_sched_barrier(0);
    {  // P1: kk = 0
      bf16x8 af[4], bf[4];
#pragma unroll
      for (int i = 0; i < 4; ++i)
        af[i] = *reinterpret_cast<const bf16x8*>(&ldsA[cur][aoff[i]]);
#pragma unroll
      for (int j = 0; j < 4; ++j)
        bf[j] = *reinterpret_cast<const bf16x8*>(&ldsB[cur][boff[j]]);
      __builtin_amdgcn_s_setprio(1);
#pragma unroll
      for (int i = 0; i < 4; ++i)
#pragma unroll
        for (int j = 0; j < 4; ++j)
          acc[i][j] = __builtin_amdgcn_mfma_f32_16x16x32_bf16(af[i], bf[j], acc[i][j], 0, 0, 0);
      __builtin_amdgcn_s_setprio(0);
    }
    {  // P2: kk = 1
      bf16x8 af[4], bf[4];
#pragma unroll
      for (int i = 0; i < 4; ++i)
        af[i] = *reinterpret_cast<const bf16x8*>(&ldsA[cur][aoff[i] + dk]);
#pragma unroll
      for (int j = 0; j < 4; ++j)
        bf[j] = *reinterpret_cast<const bf16x8*>(&ldsB[cur][boff[j] + dk]);
      __builtin_amdgcn_sched_barrier(0);
      __builtin_amdgcn_s_barrier();
      __builtin_amdgcn_sched_barrier(0);
      __builtin_amdgcn_s_setprio(1);
#pragma unroll
      for (int i = 0; i < 4; ++i)
#pragma unroll
        for (int j = 0; j < 4; ++j)
          acc[i][j] = __builtin_amdgcn_mfma_f32_16x16x32_bf16(af[i], bf[j], acc[i][j], 0, 0, 0);
      __builtin_amdgcn_s_setprio(0);
    }
  }
  asm volatile("s_waitcnt vmcnt(0)" ::: "memory");
#undef STG2

  const int rowBase = t0 + wr * 64 + fq * 4;
#pragma unroll
  for (int i = 0; i < 4; ++i)
#pragma unroll
    for (int j = 0; j < 4; ++j)
#pragma unroll
      for (int r = 0; r < 4; ++r)
        out[(size_t)(rowBase + i * 16 + r) * NH + h0 + wc * 64 + j * 16 + fr] =
            acc[i][j][r];
}

extern "C" void kernel_launch(void* const* d_in, const int* in_sizes, int n_in,
                              void* d_out, int out_size, void* d_ws, size_t ws_size,
                              hipStream_t stream) {
  const float* x = (const float*)d_in[0];    // [NT][NH]
  const float* rw = (const float*)d_in[1];   // [NT][NE]
  // d_in[2] router_indices: unused by reference (dense all-experts)
  const float* w1 = (const float*)d_in[3];   // [NE][NH][2*NI]
  const float* w2 = (const float*)d_in[4];   // [NE][NI][NH]
  float* out = (float*)d_out;

  char* ws = (char*)d_ws;
  // ws layout (bf16): Xb 16MB | W1t 48MB | W2t 24MB | inter 48MB  = 136 MiB
  unsigned short* Xb = (unsigned short*)ws;                               // [NT][NH]
  unsigned short* W1t = (unsigned short*)(ws + 16777216);                 // [NE][1536perm][NH]
  unsigned short* W2t = (unsigned short*)(ws + 16777216 + 50331648);      // [NH][NK2]
  unsigned short* inter = (unsigned short*)(ws + 16777216 + 50331648 + 25165824); // [NT][NK2]

  // 1) convert x
  k_cvt<<<dim3((NT * NH) / (256 * 8)), dim3(256), 0, stream>>>(x, Xb, (long)NT * NH);
  // 2) W1 [E][H][2I] -> W1t [E][perm(2I)][H], gate/up 16-interleaved
  k_transpose_cvt<<<dim3((2 * NI) / 32, NH / 32, NE), dim3(32, 8), 0, stream>>>(
      w1, W1t, NH, 2 * NI, (long)NH * 2 * NI, (long)2 * NI * NH, NH, 1);
  // 3) W2 [E][I][H] -> W2t [H][E*I]
  k_transpose_cvt<<<dim3(NH / 32, NI / 32, NE), dim3(32, 8), 0, stream>>>(
      w2, W2t, NI, NH, (long)NI * NH, (long)NI, NK2, 0);
  // 4) GEMM1 fused silu/up/rw -> inter (4-phase deep-cover, 256x256)
  k_gemm1<<<dim3((2 * NI) / 256, NT / 256, NE), dim3(512), 0, stream>>>(Xb, W1t, rw, inter);
  // 5) GEMM2 -> out (kk-split phases, 256x128)
  k_gemm2<<<dim3(NH / 128, NT / 256), dim3(512), 0, stream>>>(inter, W2t, out);
}

// Round 8
// 362.207 us; speedup vs baseline: 1.0251x; 1.0251x over previous
//
#include <hip/hip_runtime.h>
#include <cstdint>
#include <cstddef>

// Problem constants (Qwen3VLMoeTextExperts): E=8, H=2048, I=768, T=B*S=4096
#define NE 8
#define NH 2048
#define NI 768
#define NT 4096
#define NK2 6144   // NE*NI : K of second GEMM

typedef __bf16 bf16x8 __attribute__((ext_vector_type(8)));
typedef float f32x4 __attribute__((ext_vector_type(4)));
typedef unsigned short u16x8 __attribute__((ext_vector_type(8)));

__device__ __forceinline__ unsigned short f2bf(float f) {
  unsigned int u = __builtin_bit_cast(unsigned int, f);
  u += 0x7fffu + ((u >> 16) & 1u);   // round-to-nearest-even
  return (unsigned short)(u >> 16);
}

// async global->LDS, 16B per lane (dest must be linear: base + lane*16).
__device__ __forceinline__ void gload_lds16(const void* g, void* s) {
  __builtin_amdgcn_global_load_lds(
      (const __attribute__((address_space(1))) unsigned int*)g,
      (__attribute__((address_space(3))) unsigned int*)s, 16, 0, 0);
}

// ---------------- convert f32 -> bf16 (vectorized x8) ----------------
__global__ __launch_bounds__(256) void k_cvt(const float* __restrict__ in,
                                             unsigned short* __restrict__ out,
                                             long n) {
  long i = ((long)blockIdx.x * blockDim.x + threadIdx.x) * 8;
  if (i >= n) return;
  float4 f0 = *reinterpret_cast<const float4*>(in + i);
  float4 f1 = *reinterpret_cast<const float4*>(in + i + 4);
  u16x8 o;
  o[0] = f2bf(f0.x); o[1] = f2bf(f0.y); o[2] = f2bf(f0.z); o[3] = f2bf(f0.w);
  o[4] = f2bf(f1.x); o[5] = f2bf(f1.y); o[6] = f2bf(f1.z); o[7] = f2bf(f1.w);
  *reinterpret_cast<u16x8*>(out + i) = o;
}

// ------------- transpose + convert: out[b*oBS + perm(c)*oCS + r] = in[b][r][c] -------------
// mode 0: perm = identity. mode 1 (gate_up): interleave gate/up at 16-col
// granularity: gate col c -> (c>>4)*32 + (c&15); up col c -> (c>>4)*32 + 16 + (c&15).
__global__ __launch_bounds__(256) void k_transpose_cvt(
    const float* __restrict__ in, unsigned short* __restrict__ out,
    int R, int C, long inBS, long outBS, int outCS, int mode) {
  __shared__ float tile[32][33];
  const int b = blockIdx.z;
  const int r0 = blockIdx.y * 32, c0 = blockIdx.x * 32;
  const int tx = threadIdx.x, ty = threadIdx.y;
  const float* ib = in + (long)b * inBS;
#pragma unroll
  for (int d = 0; d < 4; d++)
    tile[ty + d * 8][tx] = ib[(long)(r0 + ty + d * 8) * C + c0 + tx];
  __syncthreads();
#pragma unroll
  for (int d = 0; d < 4; d++) {
    int c = c0 + ty + d * 8;   // original out-major index
    int r = r0 + tx;           // out minor index (coalesced)
    int orow;
    if (mode == 1) {
      int z = (c >= NI) ? 1 : 0;
      int cc = c - z * NI;
      orow = ((cc >> 4) << 5) + (z << 4) + (cc & 15);
    } else {
      orow = c;
    }
    out[(long)b * outBS + (long)orow * outCS + r] = f2bf(tile[tx][ty + d * 8]);
  }
}

// ==================== GEMM1: 4 fine phases/tile, fence-free barriers, 256x256 ====================
// Structure identical to R6 (28 ds_read_b128/tile, half-tile stages at ph1/ph2,
// vmcnt(4) at ph1/ph4 — ledger: queue is exactly 8 at every wait; vmcnt(4)
// retires the half needed next; 3 phases of HBM cover per half).
// SINGLE CHANGE vs R6: barriers are asm("s_barrier" ::: "memory") with NO
// sched_barrier(0) fences. Memory clobber keeps all ds_read / gload_lds /
// vmcnt ordering (the correctness ledger is memory-op-ordered), while pure
// register MFMAs may float across barriers/waits so the compiler can
// interleave next-phase ds_reads and MFMA clusters (m201-style scheduling).
// Collective certification argument unchanged: each wave's vmcnt retires its
// own older stage-loads before it arrives at the barrier; readers read only
// after the barrier release.

__global__ __launch_bounds__(512, 1) void k_gemm1(
    const unsigned short* __restrict__ Xb,    // [NT][NH] bf16
    const unsigned short* __restrict__ W1t,   // [NE][1536(perm)][NH] bf16
    const float* __restrict__ rw,             // [NT][NE]
    unsigned short* __restrict__ inter) {     // [NT][NK2] bf16
  __shared__ unsigned short ldsA[2][16384];   // 2 x 32 KiB
  __shared__ unsigned short ldsB[2][16384];   // 2 x 32 KiB

  const int e = blockIdx.z;
  const int t0 = blockIdx.y * 256;
  const int bn = blockIdx.x;
  const int tid = threadIdx.x;
  const int lane = tid & 63, wave = tid >> 6;
  const int wr = wave >> 2, wc = wave & 3;
  const int fr = lane & 15, fq = lane >> 4;
  const int nkt = NH / 64;                   // 32

  const unsigned short* Bg = W1t + (size_t)e * (2 * NI) * NH;
  const int rih = tid >> 3, ck = tid & 7;
  const unsigned short* sA = Xb + (size_t)(t0 + rih) * NH + ((ck ^ (rih & 7)) << 3);
  const unsigned short* sB = Bg + (size_t)(bn * 256 + rih) * NH + ((ck ^ (rih & 7)) << 3);
  const int dst = tid * 8;

// half-tile stages: H0 = A/B rows 0-127 (q=0,1), H1 = rows 128-255 (q=2,3)
#define STG_H0(C) do { \
    const int cc_ = (C); const size_t ko_ = (size_t)cc_ * 64; \
    unsigned short* da_ = &ldsA[cc_ & 1][dst]; \
    unsigned short* db_ = &ldsB[cc_ & 1][dst]; \
    gload_lds16(sB + ko_, db_); \
    gload_lds16(sB + ko_ + (size_t)(64 * NH), db_ + 4096); \
    gload_lds16(sA + ko_, da_); \
    gload_lds16(sA + ko_ + (size_t)(64 * NH), da_ + 4096); \
  } while (0)
#define STG_H1(C) do { \
    const int cc_ = (C); const size_t ko_ = (size_t)cc_ * 64; \
    unsigned short* da_ = &ldsA[cc_ & 1][dst]; \
    unsigned short* db_ = &ldsB[cc_ & 1][dst]; \
    gload_lds16(sB + ko_ + (size_t)2 * (64 * NH), db_ + 8192); \
    gload_lds16(sB + ko_ + (size_t)3 * (64 * NH), db_ + 12288); \
    gload_lds16(sA + ko_ + (size_t)2 * (64 * NH), da_ + 8192); \
    gload_lds16(sA + ko_ + (size_t)3 * (64 * NH), da_ + 12288); \
  } while (0)
#define WAITV4 asm volatile("s_waitcnt vmcnt(4)" ::: "memory")
#define BAR asm volatile("s_barrier" ::: "memory")

  f32x4 acc[8][4];
#pragma unroll
  for (int i = 0; i < 8; ++i)
#pragma unroll
    for (int j = 0; j < 4; ++j) acc[i][j] = (f32x4){0.f, 0.f, 0.f, 0.f};

  const int swz = fr & 7;
  int aoff[8], boff[4];
#pragma unroll
  for (int i = 0; i < 8; ++i)
    aoff[i] = ((i >> 2) * 128 + wr * 64 + (i & 3) * 16 + fr) * 64 + ((fq ^ swz) << 3);
#pragma unroll
  for (int j = 0; j < 4; ++j)
    boff[j] = ((j >> 1) * 128 + wc * 32 + (j & 1) * 16 + fr) * 64 + ((fq ^ swz) << 3);
  const int dk = ((((4 + fq) ^ swz) - (fq ^ swz)) << 3);   // kk=1 frag delta

  // prologue: stage tile 0 (both halves); certify H0(0); barrier
  STG_H0(0);
  STG_H1(0);
  WAITV4;
  BAR;

  for (int kt = 0; kt < nkt; ++kt) {
    const int cur = kt & 1;
    const int nx = (kt + 1 < nkt) ? kt + 1 : nkt - 1;
    const unsigned short* lA = ldsA[cur];
    const unsigned short* lB = ldsB[cur];
    bf16x8 af0[4][2], af1[4][2], bf0[2][2], bf1[2][2];

    // ---- ph1: (IH0,JH0) ----
#pragma unroll
    for (int m = 0; m < 4; ++m) {
      af0[m][0] = *reinterpret_cast<const bf16x8*>(lA + aoff[m]);
      af0[m][1] = *reinterpret_cast<const bf16x8*>(lA + aoff[m] + dk);
    }
#pragma unroll
    for (int jj = 0; jj < 2; ++jj) {
      bf0[jj][0] = *reinterpret_cast<const bf16x8*>(lB + boff[jj]);
      bf0[jj][1] = *reinterpret_cast<const bf16x8*>(lB + boff[jj] + dk);
    }
    STG_H0(nx);
    WAITV4;
    BAR;
    __builtin_amdgcn_s_setprio(1);
#pragma unroll
    for (int kk = 0; kk < 2; ++kk)
#pragma unroll
      for (int m = 0; m < 4; ++m)
#pragma unroll
        for (int jj = 0; jj < 2; ++jj)
          acc[m][jj] = __builtin_amdgcn_mfma_f32_16x16x32_bf16(af0[m][kk], bf0[jj][kk], acc[m][jj], 0, 0, 0);
    __builtin_amdgcn_s_setprio(0);

    // ---- ph2: (IH0,JH1) ----
#pragma unroll
    for (int jj = 0; jj < 2; ++jj) {
      bf1[jj][0] = *reinterpret_cast<const bf16x8*>(lB + boff[2 + jj]);
      bf1[jj][1] = *reinterpret_cast<const bf16x8*>(lB + boff[2 + jj] + dk);
    }
    STG_H1(nx);
    BAR;
    __builtin_amdgcn_s_setprio(1);
#pragma unroll
    for (int kk = 0; kk < 2; ++kk)
#pragma unroll
      for (int m = 0; m < 4; ++m)
#pragma unroll
        for (int jj = 0; jj < 2; ++jj)
          acc[m][2 + jj] = __builtin_amdgcn_mfma_f32_16x16x32_bf16(af0[m][kk], bf1[jj][kk], acc[m][2 + jj], 0, 0, 0);
    __builtin_amdgcn_s_setprio(0);

    // ---- ph3: (IH1,JH1) ----
#pragma unroll
    for (int m = 0; m < 4; ++m) {
      af1[m][0] = *reinterpret_cast<const bf16x8*>(lA + aoff[4 + m]);
      af1[m][1] = *reinterpret_cast<const bf16x8*>(lA + aoff[4 + m] + dk);
    }
    BAR;
    __builtin_amdgcn_s_setprio(1);
#pragma unroll
    for (int kk = 0; kk < 2; ++kk)
#pragma unroll
      for (int m = 0; m < 4; ++m)
#pragma unroll
        for (int jj = 0; jj < 2; ++jj)
          acc[4 + m][2 + jj] = __builtin_amdgcn_mfma_f32_16x16x32_bf16(af1[m][kk], bf1[jj][kk], acc[4 + m][2 + jj], 0, 0, 0);
    __builtin_amdgcn_s_setprio(0);

    // ---- ph4: (IH1,JH0) ----
#pragma unroll
    for (int jj = 0; jj < 2; ++jj) {
      bf0[jj][0] = *reinterpret_cast<const bf16x8*>(lB + boff[jj]);
      bf0[jj][1] = *reinterpret_cast<const bf16x8*>(lB + boff[jj] + dk);
    }
    WAITV4;
    BAR;
    __builtin_amdgcn_s_setprio(1);
#pragma unroll
    for (int kk = 0; kk < 2; ++kk)
#pragma unroll
      for (int m = 0; m < 4; ++m)
#pragma unroll
        for (int jj = 0; jj < 2; ++jj)
          acc[4 + m][jj] = __builtin_amdgcn_mfma_f32_16x16x32_bf16(af1[m][kk], bf0[jj][kk], acc[4 + m][jj], 0, 0, 0);
    __builtin_amdgcn_s_setprio(0);
  }
  asm volatile("s_waitcnt vmcnt(0)" ::: "memory");
#undef STG_H0
#undef STG_H1
#undef WAITV4
#undef BAR

  // epilogue: silu(gate)*up*rw -> bf16.  acc[i][2p]=gate, acc[i][2p+1]=up for
  // inter col (within expert) = (p*4 + wc)*16 + fr; token row from rA(i).
#pragma unroll
  for (int i = 0; i < 8; ++i) {
    const int trow = t0 + (i >> 2) * 128 + wr * 64 + (i & 3) * 16 + fq * 4;
#pragma unroll
    for (int r = 0; r < 4; ++r) {
      const int t = trow + r;
      const float rwv = rw[(size_t)t * NE + e];
#pragma unroll
      for (int p = 0; p < 2; ++p) {
        float g = acc[i][2 * p][r];
        float u = acc[i][2 * p + 1][r];
        float s = g / (1.f + __expf(-g));  // silu
        const int col = bn * 128 + (p * 4 + wc) * 16 + fr;
        inter[(size_t)t * NK2 + e * NI + col] = f2bf(rwv * u * s);
      }
    }
  }
}

// ==================== GEMM2: kk-split structure, fence-free barriers, 256x128 ====================
__global__ __launch_bounds__(512, 2) void k_gemm2(
    const unsigned short* __restrict__ inter,  // [NT][NK2] bf16
    const unsigned short* __restrict__ W2t,    // [NH][NK2] bf16
    float* __restrict__ out) {                 // [NT][NH] f32
  __shared__ unsigned short ldsA[2][16384];    // 2 x 32 KiB (256x64)
  __shared__ unsigned short ldsB[2][8192];     // 2 x 16 KiB (128x64)

  const int t0 = blockIdx.y * 256;
  const int h0 = blockIdx.x * 128;
  const int tid = threadIdx.x;
  const int lane = tid & 63, wave = tid >> 6;
  const int wr = wave >> 1, wc = wave & 1;
  const int fr = lane & 15, fq = lane >> 4;
  const int nkt = NK2 / 64;                  // 96

  const int rih = tid >> 3, ck = tid & 7;
  const unsigned short* sA = inter + (size_t)(t0 + rih) * NK2 + ((ck ^ (rih & 7)) << 3);
  const unsigned short* sB = W2t + (size_t)(h0 + rih) * NK2 + ((ck ^ (rih & 7)) << 3);
  const int dst = tid * 8;

#define STG2(C) do { \
    const int cc_ = (C); \
    unsigned short* da_ = &ldsA[cc_ & 1][dst]; \
    unsigned short* db_ = &ldsB[cc_ & 1][dst]; \
    const size_t ko_ = (size_t)cc_ * 64; \
    _Pragma("unroll") \
    for (int q = 0; q < 4; ++q) \
      gload_lds16(sA + ko_ + (size_t)q * (64 * NK2), da_ + q * 4096); \
    _Pragma("unroll") \
    for (int q = 0; q < 2; ++q) \
      gload_lds16(sB + ko_ + (size_t)q * (64 * NK2), db_ + q * 4096); \
  } while (0)

  f32x4 acc[4][4];
#pragma unroll
  for (int i = 0; i < 4; ++i)
#pragma unroll
    for (int j = 0; j < 4; ++j) acc[i][j] = (f32x4){0.f, 0.f, 0.f, 0.f};

  const int swz = fr & 7;
  int aoff[4], boff[4];
#pragma unroll
  for (int i = 0; i < 4; ++i)
    aoff[i] = (wr * 64 + i * 16 + fr) * 64 + ((fq ^ swz) << 3);
#pragma unroll
  for (int j = 0; j < 4; ++j)
    boff[j] = (wc * 64 + j * 16 + fr) * 64 + ((fq ^ swz) << 3);
  const int dk = ((((4 + fq) ^ swz) - (fq ^ swz)) << 3);

  STG2(0);
  STG2(1);

  for (int kt = 0; kt < nkt; ++kt) {
    const int cur = kt & 1;
    const int nx = (kt + 1 < nkt) ? kt + 1 : nkt - 1;
    STG2(nx);
    asm volatile("s_waitcnt vmcnt(6)" ::: "memory");
    asm volatile("s_barrier" ::: "memory");
    {  // P1: kk = 0
      bf16x8 af[4], bf[4];
#pragma unroll
      for (int i = 0; i < 4; ++i)
        af[i] = *reinterpret_cast<const bf16x8*>(&ldsA[cur][aoff[i]]);
#pragma unroll
      for (int j = 0; j < 4; ++j)
        bf[j] = *reinterpret_cast<const bf16x8*>(&ldsB[cur][boff[j]]);
      __builtin_amdgcn_s_setprio(1);
#pragma unroll
      for (int i = 0; i < 4; ++i)
#pragma unroll
        for (int j = 0; j < 4; ++j)
          acc[i][j] = __builtin_amdgcn_mfma_f32_16x16x32_bf16(af[i], bf[j], acc[i][j], 0, 0, 0);
      __builtin_amdgcn_s_setprio(0);
    }
    {  // P2: kk = 1
      bf16x8 af[4], bf[4];
#pragma unroll
      for (int i = 0; i < 4; ++i)
        af[i] = *reinterpret_cast<const bf16x8*>(&ldsA[cur][aoff[i] + dk]);
#pragma unroll
      for (int j = 0; j < 4; ++j)
        bf[j] = *reinterpret_cast<const bf16x8*>(&ldsB[cur][boff[j] + dk]);
      asm volatile("s_barrier" ::: "memory");
      __builtin_amdgcn_s_setprio(1);
#pragma unroll
      for (int i = 0; i < 4; ++i)
#pragma unroll
        for (int j = 0; j < 4; ++j)
          acc[i][j] = __builtin_amdgcn_mfma_f32_16x16x32_bf16(af[i], bf[j], acc[i][j], 0, 0, 0);
      __builtin_amdgcn_s_setprio(0);
    }
  }
  asm volatile("s_waitcnt vmcnt(0)" ::: "memory");
#undef STG2

  const int rowBase = t0 + wr * 64 + fq * 4;
#pragma unroll
  for (int i = 0; i < 4; ++i)
#pragma unroll
    for (int j = 0; j < 4; ++j)
#pragma unroll
      for (int r = 0; r < 4; ++r)
        out[(size_t)(rowBase + i * 16 + r) * NH + h0 + wc * 64 + j * 16 + fr] =
            acc[i][j][r];
}

extern "C" void kernel_launch(void* const* d_in, const int* in_sizes, int n_in,
                              void* d_out, int out_size, void* d_ws, size_t ws_size,
                              hipStream_t stream) {
  const float* x = (const float*)d_in[0];    // [NT][NH]
  const float* rw = (const float*)d_in[1];   // [NT][NE]
  // d_in[2] router_indices: unused by reference (dense all-experts)
  const float* w1 = (const float*)d_in[3];   // [NE][NH][2*NI]
  const float* w2 = (const float*)d_in[4];   // [NE][NI][NH]
  float* out = (float*)d_out;

  char* ws = (char*)d_ws;
  // ws layout (bf16): Xb 16MB | W1t 48MB | W2t 24MB | inter 48MB  = 136 MiB
  unsigned short* Xb = (unsigned short*)ws;                               // [NT][NH]
  unsigned short* W1t = (unsigned short*)(ws + 16777216);                 // [NE][1536perm][NH]
  unsigned short* W2t = (unsigned short*)(ws + 16777216 + 50331648);      // [NH][NK2]
  unsigned short* inter = (unsigned short*)(ws + 16777216 + 50331648 + 25165824); // [NT][NK2]

  // 1) convert x
  k_cvt<<<dim3((NT * NH) / (256 * 8)), dim3(256), 0, stream>>>(x, Xb, (long)NT * NH);
  // 2) W1 [E][H][2I] -> W1t [E][perm(2I)][H], gate/up 16-interleaved
  k_transpose_cvt<<<dim3((2 * NI) / 32, NH / 32, NE), dim3(32, 8), 0, stream>>>(
      w1, W1t, NH, 2 * NI, (long)NH * 2 * NI, (long)2 * NI * NH, NH, 1);
  // 3) W2 [E][I][H] -> W2t [H][E*I]
  k_transpose_cvt<<<dim3(NH / 32, NI / 32, NE), dim3(32, 8), 0, stream>>>(
      w2, W2t, NI, NH, (long)NI * NH, (long)NI, NK2, 0);
  // 4) GEMM1 fused silu/up/rw -> inter (4 fine phases, fence-free, 256x256)
  k_gemm1<<<dim3((2 * NI) / 256, NT / 256, NE), dim3(512), 0, stream>>>(Xb, W1t, rw, inter);
  // 5) GEMM2 -> out (kk-split phases, fence-free, 256x128)
  k_gemm2<<<dim3(NH / 128, NT / 256), dim3(512), 0, stream>>>(inter, W2t, out);
}

// Round 9
// 362.092 us; speedup vs baseline: 1.0254x; 1.0003x over previous
//
#include <hip/hip_runtime.h>
#include <cstdint>
#include <cstddef>

// Problem constants (Qwen3VLMoeTextExperts): E=8, H=2048, I=768, T=B*S=4096
#define NE 8
#define NH 2048
#define NI 768
#define NT 4096
#define NK2 6144   // NE*NI : K of second GEMM

typedef __bf16 bf16x8 __attribute__((ext_vector_type(8)));
typedef float f32x4 __attribute__((ext_vector_type(4)));
typedef unsigned short u16x8 __attribute__((ext_vector_type(8)));

__device__ __forceinline__ unsigned short f2bf(float f) {
  unsigned int u = __builtin_bit_cast(unsigned int, f);
  u += 0x7fffu + ((u >> 16) & 1u);   // round-to-nearest-even
  return (unsigned short)(u >> 16);
}

// async global->LDS, 16B per lane (dest must be linear: base + lane*16).
__device__ __forceinline__ void gload_lds16(const void* g, void* s) {
  __builtin_amdgcn_global_load_lds(
      (const __attribute__((address_space(1))) unsigned int*)g,
      (__attribute__((address_space(3))) unsigned int*)s, 16, 0, 0);
}

// ---------------- convert f32 -> bf16 (vectorized x8) ----------------
__global__ __launch_bounds__(256) void k_cvt(const float* __restrict__ in,
                                             unsigned short* __restrict__ out,
                                             long n) {
  long i = ((long)blockIdx.x * blockDim.x + threadIdx.x) * 8;
  if (i >= n) return;
  float4 f0 = *reinterpret_cast<const float4*>(in + i);
  float4 f1 = *reinterpret_cast<const float4*>(in + i + 4);
  u16x8 o;
  o[0] = f2bf(f0.x); o[1] = f2bf(f0.y); o[2] = f2bf(f0.z); o[3] = f2bf(f0.w);
  o[4] = f2bf(f1.x); o[5] = f2bf(f1.y); o[6] = f2bf(f1.z); o[7] = f2bf(f1.w);
  *reinterpret_cast<u16x8*>(out + i) = o;
}

// ------------- transpose + convert: out[b*oBS + perm(c)*oCS + r] = in[b][r][c] -------------
// mode 0: perm = identity. mode 1 (gate_up): interleave gate/up at 16-col
// granularity: gate col c -> (c>>4)*32 + (c&15); up col c -> (c>>4)*32 + 16 + (c&15).
__global__ __launch_bounds__(256) void k_transpose_cvt(
    const float* __restrict__ in, unsigned short* __restrict__ out,
    int R, int C, long inBS, long outBS, int outCS, int mode) {
  __shared__ float tile[32][33];
  const int b = blockIdx.z;
  const int r0 = blockIdx.y * 32, c0 = blockIdx.x * 32;
  const int tx = threadIdx.x, ty = threadIdx.y;
  const float* ib = in + (long)b * inBS;
#pragma unroll
  for (int d = 0; d < 4; d++)
    tile[ty + d * 8][tx] = ib[(long)(r0 + ty + d * 8) * C + c0 + tx];
  __syncthreads();
#pragma unroll
  for (int d = 0; d < 4; d++) {
    int c = c0 + ty + d * 8;   // original out-major index
    int r = r0 + tx;           // out minor index (coalesced)
    int orow;
    if (mode == 1) {
      int z = (c >= NI) ? 1 : 0;
      int cc = c - z * NI;
      orow = ((cc >> 4) << 5) + (z << 4) + (cc & 15);
    } else {
      orow = c;
    }
    out[(long)b * outBS + (long)orow * outCS + r] = f2bf(tile[tx][ty + d * 8]);
  }
}

// ==================== GEMM1: single-barrier K-tile, compiler-scheduled, 256x256 ====================
// 8 waves: wr=wave>>2 (M), wc=wave&3 (N); per-wave out 128x64 (M-interleaved).
// rA(i)=(i>>2)*128+wr*64+(i&3)*16+fr, rB(j)=(j>>1)*128+wc*32+(j&1)*16+fr.
// Per K-tile kt (read buf c=kt&1, stage buf 1-c):
//   { 24 ds_read_b128 (all fragments) ; STG(kt+1) 8 gloads (skip on last) ;
//     64 MFMA ; vmcnt(0) ; s_barrier }
// NO intra-tile barriers / sched_barriers / setprio — the compiler emits
// counted lgkmcnt between ds_read and dependent MFMA and is free to
// interleave LDS reads, stage issues, and MFMAs within the region, so the
// LDS port and matrix pipe overlap (the R4-R8 per-phase barriers forbade
// this; all plateaued at 44-46% MfmaUtil).
// Correctness: 2-buffer invariant. Reads of buf c at tile kt are certified
// by tile kt-1's {vmcnt(0); s_barrier} (stage of tile kt issued during tile
// kt-1 and fully drained there). Stage into buf 1-c targets regions whose
// last readers (tile kt-1) passed the tile-kt-entry barrier. vmcnt(0) drain
// is ~free: the loads it waits on were issued a full tile (~2000 cyc) ago.
// Swizzle: chunk ck of row r stored at ck^(r&7), pre-swizzled global source;
// read key fr&7. 0 bank conflicts (measured R2-R8).

__global__ __launch_bounds__(512, 1) void k_gemm1(
    const unsigned short* __restrict__ Xb,    // [NT][NH] bf16
    const unsigned short* __restrict__ W1t,   // [NE][1536(perm)][NH] bf16
    const float* __restrict__ rw,             // [NT][NE]
    unsigned short* __restrict__ inter) {     // [NT][NK2] bf16
  __shared__ unsigned short ldsA[2][16384];   // 2 x 32 KiB
  __shared__ unsigned short ldsB[2][16384];   // 2 x 32 KiB

  const int e = blockIdx.z;
  const int t0 = blockIdx.y * 256;
  const int bn = blockIdx.x;
  const int tid = threadIdx.x;
  const int lane = tid & 63, wave = tid >> 6;
  const int wr = wave >> 2, wc = wave & 3;
  const int fr = lane & 15, fq = lane >> 4;
  const int nkt = NH / 64;                   // 32

  const unsigned short* Bg = W1t + (size_t)e * (2 * NI) * NH;
  const int rih = tid >> 3, ck = tid & 7;
  const unsigned short* sA = Xb + (size_t)(t0 + rih) * NH + ((ck ^ (rih & 7)) << 3);
  const unsigned short* sB = Bg + (size_t)(bn * 256 + rih) * NH + ((ck ^ (rih & 7)) << 3);
  const int dst = tid * 8;

#define STG1(C) do { \
    const int cc_ = (C); const size_t ko_ = (size_t)cc_ * 64; \
    unsigned short* da_ = &ldsA[cc_ & 1][dst]; \
    unsigned short* db_ = &ldsB[cc_ & 1][dst]; \
    _Pragma("unroll") \
    for (int q = 0; q < 4; ++q) { \
      gload_lds16(sA + ko_ + (size_t)q * (64 * NH), da_ + q * 4096); \
      gload_lds16(sB + ko_ + (size_t)q * (64 * NH), db_ + q * 4096); \
    } \
  } while (0)

  f32x4 acc[8][4];
#pragma unroll
  for (int i = 0; i < 8; ++i)
#pragma unroll
    for (int j = 0; j < 4; ++j) acc[i][j] = (f32x4){0.f, 0.f, 0.f, 0.f};

  const int swz = fr & 7;
  int aoff[8], boff[4];
#pragma unroll
  for (int i = 0; i < 8; ++i)
    aoff[i] = ((i >> 2) * 128 + wr * 64 + (i & 3) * 16 + fr) * 64 + ((fq ^ swz) << 3);
#pragma unroll
  for (int j = 0; j < 4; ++j)
    boff[j] = ((j >> 1) * 128 + wc * 32 + (j & 1) * 16 + fr) * 64 + ((fq ^ swz) << 3);
  const int dk = ((((4 + fq) ^ swz) - (fq ^ swz)) << 3);   // kk=1 frag delta

  // prologue: stage tile 0, drain, barrier
  STG1(0);
  asm volatile("s_waitcnt vmcnt(0)" ::: "memory");
  asm volatile("s_barrier" ::: "memory");

  for (int kt = 0; kt < nkt; ++kt) {
    const int cur = kt & 1;
    const unsigned short* lA = ldsA[cur];
    const unsigned short* lB = ldsB[cur];

    // all fragment reads for this tile (24 ds_read_b128)
    bf16x8 af[8][2], bf[4][2];
#pragma unroll
    for (int m = 0; m < 8; ++m) {
      af[m][0] = *reinterpret_cast<const bf16x8*>(lA + aoff[m]);
      af[m][1] = *reinterpret_cast<const bf16x8*>(lA + aoff[m] + dk);
    }
#pragma unroll
    for (int j = 0; j < 4; ++j) {
      bf[j][0] = *reinterpret_cast<const bf16x8*>(lB + boff[j]);
      bf[j][1] = *reinterpret_cast<const bf16x8*>(lB + boff[j] + dk);
    }

    // stage next tile into the other buffer (none on the last tile)
    if (kt + 1 < nkt) STG1(kt + 1);

    // 64 MFMA — compiler interleaves with the reads via counted lgkmcnt
#pragma unroll
    for (int kk = 0; kk < 2; ++kk)
#pragma unroll
      for (int m = 0; m < 8; ++m)
#pragma unroll
        for (int j = 0; j < 4; ++j)
          acc[m][j] = __builtin_amdgcn_mfma_f32_16x16x32_bf16(af[m][kk], bf[j][kk], acc[m][j], 0, 0, 0);

    asm volatile("s_waitcnt vmcnt(0)" ::: "memory");
    asm volatile("s_barrier" ::: "memory");
  }
#undef STG1

  // epilogue: silu(gate)*up*rw -> bf16.  acc[i][2p]=gate, acc[i][2p+1]=up for
  // inter col (within expert) = (p*4 + wc)*16 + fr; token row from rA(i).
#pragma unroll
  for (int i = 0; i < 8; ++i) {
    const int trow = t0 + (i >> 2) * 128 + wr * 64 + (i & 3) * 16 + fq * 4;
#pragma unroll
    for (int r = 0; r < 4; ++r) {
      const int t = trow + r;
      const float rwv = rw[(size_t)t * NE + e];
#pragma unroll
      for (int p = 0; p < 2; ++p) {
        float g = acc[i][2 * p][r];
        float u = acc[i][2 * p + 1][r];
        float s = g / (1.f + __expf(-g));  // silu
        const int col = bn * 128 + (p * 4 + wc) * 16 + fr;
        inter[(size_t)t * NK2 + e * NI + col] = f2bf(rwv * u * s);
      }
    }
  }
}

// ==================== GEMM2: single-barrier K-tile, 256x128 ====================
__global__ __launch_bounds__(512, 1) void k_gemm2(
    const unsigned short* __restrict__ inter,  // [NT][NK2] bf16
    const unsigned short* __restrict__ W2t,    // [NH][NK2] bf16
    float* __restrict__ out) {                 // [NT][NH] f32
  __shared__ unsigned short ldsA[2][16384];    // 2 x 32 KiB (256x64)
  __shared__ unsigned short ldsB[2][8192];     // 2 x 16 KiB (128x64)

  const int t0 = blockIdx.y * 256;
  const int h0 = blockIdx.x * 128;
  const int tid = threadIdx.x;
  const int lane = tid & 63, wave = tid >> 6;
  const int wr = wave >> 1, wc = wave & 1;
  const int fr = lane & 15, fq = lane >> 4;
  const int nkt = NK2 / 64;                  // 96

  const int rih = tid >> 3, ck = tid & 7;
  const unsigned short* sA = inter + (size_t)(t0 + rih) * NK2 + ((ck ^ (rih & 7)) << 3);
  const unsigned short* sB = W2t + (size_t)(h0 + rih) * NK2 + ((ck ^ (rih & 7)) << 3);
  const int dst = tid * 8;

#define STG2(C) do { \
    const int cc_ = (C); \
    unsigned short* da_ = &ldsA[cc_ & 1][dst]; \
    unsigned short* db_ = &ldsB[cc_ & 1][dst]; \
    const size_t ko_ = (size_t)cc_ * 64; \
    _Pragma("unroll") \
    for (int q = 0; q < 4; ++q) \
      gload_lds16(sA + ko_ + (size_t)q * (64 * NK2), da_ + q * 4096); \
    _Pragma("unroll") \
    for (int q = 0; q < 2; ++q) \
      gload_lds16(sB + ko_ + (size_t)q * (64 * NK2), db_ + q * 4096); \
  } while (0)

  f32x4 acc[4][4];
#pragma unroll
  for (int i = 0; i < 4; ++i)
#pragma unroll
    for (int j = 0; j < 4; ++j) acc[i][j] = (f32x4){0.f, 0.f, 0.f, 0.f};

  const int swz = fr & 7;
  int aoff[4], boff[4];
#pragma unroll
  for (int i = 0; i < 4; ++i)
    aoff[i] = (wr * 64 + i * 16 + fr) * 64 + ((fq ^ swz) << 3);
#pragma unroll
  for (int j = 0; j < 4; ++j)
    boff[j] = (wc * 64 + j * 16 + fr) * 64 + ((fq ^ swz) << 3);
  const int dk = ((((4 + fq) ^ swz) - (fq ^ swz)) << 3);

  STG2(0);
  asm volatile("s_waitcnt vmcnt(0)" ::: "memory");
  asm volatile("s_barrier" ::: "memory");

  for (int kt = 0; kt < nkt; ++kt) {
    const int cur = kt & 1;
    const unsigned short* lA = ldsA[cur];
    const unsigned short* lB = ldsB[cur];

    bf16x8 af[4][2], bf[4][2];
#pragma unroll
    for (int i = 0; i < 4; ++i) {
      af[i][0] = *reinterpret_cast<const bf16x8*>(lA + aoff[i]);
      af[i][1] = *reinterpret_cast<const bf16x8*>(lA + aoff[i] + dk);
    }
#pragma unroll
    for (int j = 0; j < 4; ++j) {
      bf[j][0] = *reinterpret_cast<const bf16x8*>(lB + boff[j]);
      bf[j][1] = *reinterpret_cast<const bf16x8*>(lB + boff[j] + dk);
    }

    if (kt + 1 < nkt) STG2(kt + 1);

#pragma unroll
    for (int kk = 0; kk < 2; ++kk)
#pragma unroll
      for (int i = 0; i < 4; ++i)
#pragma unroll
        for (int j = 0; j < 4; ++j)
          acc[i][j] = __builtin_amdgcn_mfma_f32_16x16x32_bf16(af[i][kk], bf[j][kk], acc[i][j], 0, 0, 0);

    asm volatile("s_waitcnt vmcnt(0)" ::: "memory");
    asm volatile("s_barrier" ::: "memory");
  }
#undef STG2

  const int rowBase = t0 + wr * 64 + fq * 4;
#pragma unroll
  for (int i = 0; i < 4; ++i)
#pragma unroll
    for (int j = 0; j < 4; ++j)
#pragma unroll
      for (int r = 0; r < 4; ++r)
        out[(size_t)(rowBase + i * 16 + r) * NH + h0 + wc * 64 + j * 16 + fr] =
            acc[i][j][r];
}

extern "C" void kernel_launch(void* const* d_in, const int* in_sizes, int n_in,
                              void* d_out, int out_size, void* d_ws, size_t ws_size,
                              hipStream_t stream) {
  const float* x = (const float*)d_in[0];    // [NT][NH]
  const float* rw = (const float*)d_in[1];   // [NT][NE]
  // d_in[2] router_indices: unused by reference (dense all-experts)
  const float* w1 = (const float*)d_in[3];   // [NE][NH][2*NI]
  const float* w2 = (const float*)d_in[4];   // [NE][NI][NH]
  float* out = (float*)d_out;

  char* ws = (char*)d_ws;
  // ws layout (bf16): Xb 16MB | W1t 48MB | W2t 24MB | inter 48MB  = 136 MiB
  unsigned short* Xb = (unsigned short*)ws;                               // [NT][NH]
  unsigned short* W1t = (unsigned short*)(ws + 16777216);                 // [NE][1536perm][NH]
  unsigned short* W2t = (unsigned short*)(ws + 16777216 + 50331648);      // [NH][NK2]
  unsigned short* inter = (unsigned short*)(ws + 16777216 + 50331648 + 25165824); // [NT][NK2]

  // 1) convert x
  k_cvt<<<dim3((NT * NH) / (256 * 8)), dim3(256), 0, stream>>>(x, Xb, (long)NT * NH);
  // 2) W1 [E][H][2I] -> W1t [E][perm(2I)][H], gate/up 16-interleaved
  k_transpose_cvt<<<dim3((2 * NI) / 32, NH / 32, NE), dim3(32, 8), 0, stream>>>(
      w1, W1t, NH, 2 * NI, (long)NH * 2 * NI, (long)2 * NI * NH, NH, 1);
  // 3) W2 [E][I][H] -> W2t [H][E*I]
  k_transpose_cvt<<<dim3(NH / 32, NI / 32, NE), dim3(32, 8), 0, stream>>>(
      w2, W2t, NI, NH, (long)NI * NH, (long)NI, NK2, 0);
  // 4) GEMM1 fused silu/up/rw -> inter (single-barrier K-tile, 256x256)
  k_gemm1<<<dim3((2 * NI) / 256, NT / 256, NE), dim3(512), 0, stream>>>(Xb, W1t, rw, inter);
  // 5) GEMM2 -> out (single-barrier K-tile, 256x128)
  k_gemm2<<<dim3(NH / 128, NT / 256), dim3(512), 0, stream>>>(inter, W2t, out);
}